// Round 3
// baseline (231.109 us; speedup 1.0000x reference)
//
#include <hip/hip_runtime.h>

#define L2E 1.4426950408889634f   // log2(e)

typedef float v2f __attribute__((ext_vector_type(2)));

__device__ __forceinline__ v2f exp2v(v2f a) {
    v2f r; r.x = __builtin_amdgcn_exp2f(a.x); r.y = __builtin_amdgcn_exp2f(a.y); return r;
}
__device__ __forceinline__ v2f rcpv(v2f a) {
    v2f r; r.x = __builtin_amdgcn_rcpf(a.x); r.y = __builtin_amdgcn_rcpf(a.y); return r;
}
__device__ __forceinline__ v2f fmav(v2f a, v2f b, v2f c) {
    return __builtin_elementwise_fma(a, b, c);
}
// tanh via [5/4] Pade: exact to ~5e-8 for |x|<=1 (inputs here are in (-1,1))
__device__ __forceinline__ v2f tanh_pade(v2f xv) {
    v2f x2 = xv * xv;
    v2f num = xv * (945.0f + x2 * (105.0f + x2));
    v2f den = 945.0f + x2 * (420.0f + 15.0f * x2);
    return num * rcpv(den);
}

// ---------------------------------------------------------------------------
// Workspace layout in v2f (8B) units; every slot holds a DUPLICATED value so a
// uniform s_load_dwordx2 delivers a ready-made splat pair (zero v_movs, and the
// compiler may use it directly as a packed-FMA operand).
//   v2f[0   .. 576)   cell1 W   ((j*3+g)*16 + k)
//   v2f[576 ..1008)   cell2 W   ((j*3+g)*12 + k)
//   v2f[1008..1440)   cellm W
//   v2f[1440..1872)   celld W
//   v2f[1872..2016)   biases: 4 cells x (j*3+g), pre-added b_ih+b_hh, prescaled
// Gate scales fold the exp2 args: i,o -> -log2e ; g -> -2*log2e, so
// exp2(acc) == e^{-gate} (i,o) and e^{-2*gate} (g). f gate dead (c0=0).
// Total: 2016 v2f = 16128 bytes.
// ---------------------------------------------------------------------------
__global__ void prep_kernel(
    const float* __restrict__ W1, const float* __restrict__ bi1, const float* __restrict__ bh1,
    const float* __restrict__ W2, const float* __restrict__ bi2, const float* __restrict__ bh2,
    const float* __restrict__ Wm, const float* __restrict__ bim, const float* __restrict__ bhm,
    const float* __restrict__ Wd, const float* __restrict__ bid, const float* __restrict__ bhd,
    float* __restrict__ ws)
{
    const float* Ws[4]  = {W1, W2, Wm, Wd};
    const float* bis[4] = {bi1, bi2, bim, bid};
    const float* bhs[4] = {bh1, bh2, bhm, bhd};
    const int   goff[3] = {0, 24, 36};
    const float gsc[3]  = {-L2E, -2.0f * L2E, -L2E};

    int t = blockIdx.x * blockDim.x + threadIdx.x;
    if (t < 1872) {
        int c, base, K;
        if (t < 576)       { c = 0; base = 0;    K = 16; }
        else if (t < 1008) { c = 1; base = 576;  K = 12; }
        else if (t < 1440) { c = 2; base = 1008; K = 12; }
        else               { c = 3; base = 1440; K = 12; }
        int pi = t - base;
        int k  = pi % K;
        int g  = (pi / K) % 3;
        int j  = pi / (3 * K);
        float v = gsc[g] * Ws[c][(goff[g] + j) * K + k];
        ws[2 * t] = v; ws[2 * t + 1] = v;
    } else if (t < 2016) {
        int u = t - 1872;
        int c = u / 36;
        int v0 = u % 36;
        int j = v0 / 3, g = v0 % 3;
        float v = gsc[g] * (bis[c][goff[g] + j] + bhs[c][goff[g] + j]);
        ws[2 * t] = v; ws[2 * t + 1] = v;
    }
}

// One LSTM cell (zero state). v2f lanes = (row0, row1) pair; weights arrive as
// duplicated v2f pairs from uniform s_loads.
//   c = sig(i)*tanh(g) = (1-tg) * rcp((1+ei)(1+tg))      [merged rcp]
//   h = sig(o)*tanh(c) = c*P(c^2) * rcp((1+eo)*Q(c^2))   [merged rcp + Pade]
template <int K>
__device__ __forceinline__ void cell_core(const v2f* __restrict__ w,
                                          const v2f* __restrict__ b,
                                          const v2f* xs, v2f h[12])
{
#pragma unroll
    for (int j = 0; j < 12; ++j) {
        const v2f* wj = w + j * 3 * K;
        v2f ai = b[j * 3 + 0], ag = b[j * 3 + 1], ao = b[j * 3 + 2];
#pragma unroll
        for (int k = 0; k < K; ++k) {
            ai = fmav(wj[k],         xs[k], ai);
            ag = fmav(wj[K + k],     xs[k], ag);
            ao = fmav(wj[2 * K + k], xs[k], ao);
        }
        v2f ei = exp2v(ai);
        v2f tg = exp2v(ag);
        v2f eo = exp2v(ao);
        v2f rig = rcpv((1.0f + ei) * (1.0f + tg));
        v2f c   = (1.0f - tg) * rig;             // sig(i)*tanh(g), in (-1,1)
        v2f c2  = c * c;
        v2f num = c * (945.0f + c2 * (105.0f + c2));
        v2f den = 945.0f + c2 * (420.0f + 15.0f * c2);
        v2f ro  = rcpv((1.0f + eo) * den);       // sig(o) merged with Pade den
        h[j]    = num * ro;                      // sig(o)*tanh(c), in (-1,1)
    }
}

__global__ __launch_bounds__(256) void dynnet_kernel(
    const float* __restrict__ x, const float* __restrict__ wsf,
    float* __restrict__ out, int nrows)
{
    int t = blockIdx.x * blockDim.x + threadIdx.x;
    int half = nrows >> 1;
    if (t >= half) return;

    const v2f* wv = (const v2f*)wsf;
    const v2f* W1 = wv;        const v2f* W2 = wv + 576;
    const v2f* Wm = wv + 1008; const v2f* Wd = wv + 1440;
    const v2f* B1 = wv + 1872; const v2f* B2 = wv + 1908;
    const v2f* Bm = wv + 1944; const v2f* Bd = wv + 1980;

    // rows t and t+half, interleaved into v2f lanes
    v2f xs[16];
    const float4* xa = (const float4*)(x + (size_t)t * 16);
    const float4* xb = (const float4*)(x + (size_t)(t + half) * 16);
#pragma unroll
    for (int i = 0; i < 4; ++i) {
        float4 a = xa[i], b = xb[i];
        xs[4 * i + 0] = (v2f){a.x, b.x};
        xs[4 * i + 1] = (v2f){a.y, b.y};
        xs[4 * i + 2] = (v2f){a.z, b.z};
        xs[4 * i + 3] = (v2f){a.w, b.w};
    }

    v2f h[12], g[12];

    // cell 1 -> relu (h feeds cell2 directly; no repacking needed)
    cell_core<16>(W1, B1, xs, h);
#pragma unroll
    for (int j = 0; j < 12; ++j) h[j] = __builtin_elementwise_max(h[j], (v2f)0.0f);

    // cell 2 -> selu
    cell_core<12>(W2, B2, h, g);
#pragma unroll
    for (int j = 0; j < 12; ++j) {
        v2f v  = g[j];                        // in (-1,1): e^v safe
        v2f ev = exp2v(v * L2E);
        v2f ng = fmav(ev, (v2f)1.7580993408473766f, (v2f)(-1.7580993408473766f));
        v2f ps = v * 1.0507009873554805f;
        v2f s;
        s.x = v.x > 0.0f ? ps.x : ng.x;
        s.y = v.y > 0.0f ? ps.y : ng.y;
        g[j] = s;
    }

    // heads m, d -> final tanh (bounded input -> Pade)
    v2f hm[12], hd[12];
    cell_core<12>(Wm, Bm, g, hm);
    cell_core<12>(Wd, Bd, g, hd);

    v2f tm[12], td[12];
#pragma unroll
    for (int j = 0; j < 12; ++j) {
        tm[j] = tanh_pade(hm[j]);
        td[j] = tanh_pade(hd[j]);
    }

    // out = concat([m, dv], axis=0); .x -> row t, .y -> row t+half
    float4* om0 = (float4*)(out + (size_t)t * 12);
    float4* om1 = (float4*)(out + (size_t)(t + half) * 12);
    float4* od0 = (float4*)(out + ((size_t)nrows + t) * 12);
    float4* od1 = (float4*)(out + ((size_t)nrows + t + half) * 12);
    om0[0] = make_float4(tm[0].x, tm[1].x, tm[2].x,  tm[3].x);
    om0[1] = make_float4(tm[4].x, tm[5].x, tm[6].x,  tm[7].x);
    om0[2] = make_float4(tm[8].x, tm[9].x, tm[10].x, tm[11].x);
    om1[0] = make_float4(tm[0].y, tm[1].y, tm[2].y,  tm[3].y);
    om1[1] = make_float4(tm[4].y, tm[5].y, tm[6].y,  tm[7].y);
    om1[2] = make_float4(tm[8].y, tm[9].y, tm[10].y, tm[11].y);
    od0[0] = make_float4(td[0].x, td[1].x, td[2].x,  td[3].x);
    od0[1] = make_float4(td[4].x, td[5].x, td[6].x,  td[7].x);
    od0[2] = make_float4(td[8].x, td[9].x, td[10].x, td[11].x);
    od1[0] = make_float4(td[0].y, td[1].y, td[2].y,  td[3].y);
    od1[1] = make_float4(td[4].y, td[5].y, td[6].y,  td[7].y);
    od1[2] = make_float4(td[8].y, td[9].y, td[10].y, td[11].y);
}

extern "C" void kernel_launch(void* const* d_in, const int* in_sizes, int n_in,
                              void* d_out, int out_size, void* d_ws, size_t ws_size,
                              hipStream_t stream) {
    const float* x    = (const float*)d_in[0];
    const float* Wih1 = (const float*)d_in[1];
    const float* bih1 = (const float*)d_in[2];
    const float* bhh1 = (const float*)d_in[3];
    const float* Wih2 = (const float*)d_in[4];
    const float* bih2 = (const float*)d_in[5];
    const float* bhh2 = (const float*)d_in[6];
    const float* Wihm = (const float*)d_in[7];
    const float* bihm = (const float*)d_in[8];
    const float* bhhm = (const float*)d_in[9];
    const float* Wihd = (const float*)d_in[10];
    const float* bihd = (const float*)d_in[11];
    const float* bhhd = (const float*)d_in[12];
    float* out = (float*)d_out;
    float* ws  = (float*)d_ws;   // needs 2016 v2f = 16128 B

    prep_kernel<<<8, 256, 0, stream>>>(Wih1, bih1, bhh1, Wih2, bih2, bhh2,
                                       Wihm, bihm, bhhm, Wihd, bihd, bhhd, ws);

    int nrows = in_sizes[0] / 16;  // B = 1048576
    int half  = nrows >> 1;
    int block = 256;
    int grid  = (half + block - 1) / block;  // 2048
    dynnet_kernel<<<grid, block, 0, stream>>>(x, ws, out, nrows);
}

// Round 4
// 206.738 us; speedup vs baseline: 1.1179x; 1.1179x over previous
//
#include <hip/hip_runtime.h>

#define L2E 1.4426950408889634f

typedef float  f32x4  __attribute__((ext_vector_type(4)));
typedef short  bf16x8 __attribute__((ext_vector_type(8)));

__device__ __forceinline__ float ex2(float x){ return __builtin_amdgcn_exp2f(x); }
__device__ __forceinline__ float rcpf_(float x){ return __builtin_amdgcn_rcpf(x); }
// round-to-nearest-even f32 -> bf16 (finite inputs only)
__device__ __forceinline__ unsigned short f2bf(float f){
    unsigned u = __float_as_uint(f);
    u = (u + 0x7FFFu + ((u >> 16) & 1u)) >> 16;
    return (unsigned short)u;
}
__device__ __forceinline__ float bf2f(unsigned short h){
    return __uint_as_float(((unsigned)h) << 16);
}

union FragCast { uint4 u; bf16x8 v; };

// Gates arrive pre-scaled (i,o: -log2e ; g: -2log2e) so exp2 gives e^-i etc.
//   c = sig(i)*tanh(g) = (1-tg) * rcp((1+ei)(1+tg))
//   h = sig(o)*tanh(c) = c*P(c^2) * rcp((1+eo)*Q(c^2))   [Pade, |c|<1]
__device__ __forceinline__ float cell_act(f32x4 d){
    float ei = ex2(d.x), tg = ex2(d.y), eo = ex2(d.z);
    float rig = rcpf_((1.0f+ei)*(1.0f+tg));
    float c   = (1.0f-tg)*rig;
    float c2  = c*c;
    float num = c*(945.0f + c2*(105.0f + c2));
    float den = 945.0f + c2*(420.0f + 15.0f*c2);
    return num * rcpf_((1.0f+eo)*den);
}
__device__ __forceinline__ float tanh_pade(float x){
    float x2 = x*x;
    return x*(945.0f + x2*(105.0f + x2)) * rcpf_(945.0f + x2*(420.0f + 15.0f*x2));
}

// ---------------------------------------------------------------------------
// ws layout:
//  bytes [0, 24576): 24 A-fragments, 1024B each, frag id f=((c*3+mb)*2+p).
//    Element for lane l (0..63), e (0..7): A[m][k], m=mb*16+(l&15), k=8*(l>>4)+e.
//    Gate rows interleaved (i,g,o,pad)*12 -> gr=mb*16+m; t=gr&3; j=gr>>2.
//    p=0: [Whi | Whi] (+bias hi/lo at k=12/13 for cells 2-4); p=1: [Wlo | 0].
//  bytes [24576, 27648): cell1 bias C-init frags: mb,lane -> f32x4 =
//    biasvec1[mb*16 + (l>>4)*4 + r]  (i,g,o,0 interleaved, prescaled)
// ---------------------------------------------------------------------------
__global__ void prep_kernel(
    const float* __restrict__ W1, const float* __restrict__ bi1, const float* __restrict__ bh1,
    const float* __restrict__ W2, const float* __restrict__ bi2, const float* __restrict__ bh2,
    const float* __restrict__ Wm, const float* __restrict__ bim, const float* __restrict__ bhm,
    const float* __restrict__ Wd, const float* __restrict__ bid, const float* __restrict__ bhd,
    unsigned short* __restrict__ wsA, float* __restrict__ wsB1)
{
    const float* Ws[4]  = {W1, W2, Wm, Wd};
    const float* bis[4] = {bi1, bi2, bim, bid};
    const float* bhs[4] = {bh1, bh2, bhm, bhd};
    const int goff[3] = {0, 24, 36};

    int t = blockIdx.x * blockDim.x + threadIdx.x;
    if (t < 12288) {
        int fragid = t >> 9;          // 512 elems per frag
        int le = t & 511;
        int l  = le >> 3, e = le & 7;
        int p  = fragid & 1;
        int cmb = fragid >> 1;
        int c  = cmb / 3, mb = cmb % 3;
        int m  = l & 15, kg = l >> 4;
        int k  = kg * 8 + e;
        int gr = mb * 16 + m;
        int t3 = gr & 3, j = gr >> 2;
        int K  = (c == 0) ? 16 : 12;
        int col = (k < 16) ? k : (k - 16);
        unsigned short outv = 0;
        if (t3 < 3) {
            float gscv = (t3 == 1) ? (-2.0f * L2E) : (-L2E);
            bool biasslot = (c > 0) && (k < 16) && (col == 12 || col == 13);
            float full = 0.0f;
            if (col < K)        full = gscv * Ws[c][(goff[t3] + j) * K + col];
            else if (biasslot)  full = gscv * (bis[c][goff[t3] + j] + bhs[c][goff[t3] + j]);
            if (p == 0) {
                unsigned short hi = f2bf(full);
                outv = (biasslot && col == 13) ? f2bf(full - bf2f(hi)) : hi;
            } else {
                if (k < 16 && col < K) {
                    unsigned short hi = f2bf(full);
                    outv = f2bf(full - bf2f(hi));
                }
            }
        }
        wsA[t] = outv;
    } else if (t < 13056) {
        int u = t - 12288;
        int r = u & 3, v = u >> 2;
        int l = v & 63, mb = v >> 6;
        float val = 0.0f;
        if (r < 3) {
            int gr = mb * 16 + ((l >> 4) * 4) + r;   // t3 == r
            int j  = gr >> 2;
            float gscv = (r == 1) ? (-2.0f * L2E) : (-L2E);
            val = gscv * (bis[0][goff[r] + j] + bhs[0][goff[r] + j]);
        }
        wsB1[u] = val;
    }
}

__global__ __launch_bounds__(256, 2) void dynnet_kernel(
    const float* __restrict__ x, const unsigned short* __restrict__ wsA,
    const float* __restrict__ wsB1, float* __restrict__ out, int nrows)
{
    // per-wave double buffer: 16 rows x 40 ushort (80B stride: 16B-aligned,
    // bank-spread). slots 0..11 hi(h_j), 12,13 = 1.0 (bias lane), 14,15 = 0,
    // 16..27 lo(h_j), 28..31 = 0.
    __shared__ __align__(16) unsigned short lds[4][2][640];
    const int lane = threadIdx.x & 63;
    const int wid  = threadIdx.x >> 6;
    const int n    = lane & 15;
    const int kg   = lane >> 4;
    unsigned short* bufA = &lds[wid][0][0];
    unsigned short* bufB = &lds[wid][1][0];

    if (lane < 16) {   // constant pad slots, written once, never overwritten
        *(unsigned long long*)&bufA[lane*40 + 12] = 0x3F803F80ULL; // 1.0,1.0,0,0
        *(unsigned long long*)&bufA[lane*40 + 28] = 0ULL;
        *(unsigned long long*)&bufB[lane*40 + 12] = 0x3F803F80ULL;
        *(unsigned long long*)&bufB[lane*40 + 28] = 0ULL;
    }

    // persistent weight fragments (96 VGPR) + cell1 bias C-init (12 VGPR)
    bf16x8 Afr[24];
    const uint4* wsA4 = (const uint4*)wsA;
#pragma unroll
    for (int f = 0; f < 24; ++f) {
        FragCast fc; fc.u = wsA4[f*64 + lane]; Afr[f] = fc.v;
    }
    f32x4 b1[3];
    const float4* wsB14 = (const float4*)wsB1;
#pragma unroll
    for (int mb = 0; mb < 3; ++mb) {
        float4 tb = wsB14[mb*64 + lane];
        b1[mb] = (f32x4){tb.x, tb.y, tb.z, tb.w};
    }

    const int ntiles = nrows >> 4;
    const int nw = gridDim.x * 4;
    int tile = blockIdx.x * 4 + wid;
    if (tile >= ntiles) return;

    float4 xv0, xv1;
    {
        const float* xp = x + (size_t)(tile*16 + n)*16 + (kg & 1)*8;
        xv0 = ((const float4*)xp)[0];
        xv1 = ((const float4*)xp)[1];
    }

    const f32x4 z4 = {0.f, 0.f, 0.f, 0.f};

    for (; tile < ntiles; tile += nw) {
        // B-fragment for cell1: k 0..15 = xhi, 16..31 = xlo
        float xe[8] = {xv0.x,xv0.y,xv0.z,xv0.w, xv1.x,xv1.y,xv1.z,xv1.w};
        bf16x8 xB;
        const bool wantlo = (kg >= 2);
#pragma unroll
        for (int e = 0; e < 8; ++e) {
            unsigned short hi = f2bf(xe[e]);
            unsigned short v  = wantlo ? f2bf(xe[e] - bf2f(hi)) : hi;
            xB[e] = (short)v;
        }

        const int row0 = tile*16 + n;

        // ---- cell 1 (K=16, bias via C-init) -> relu -> bufA ----
#pragma unroll
        for (int mb = 0; mb < 3; ++mb) {
            f32x4 acc = __builtin_amdgcn_mfma_f32_16x16x32_bf16(Afr[mb*2+0], xB, b1[mb], 0,0,0);
            acc       = __builtin_amdgcn_mfma_f32_16x16x32_bf16(Afr[mb*2+1], xB, acc,    0,0,0);
            float h = fmaxf(cell_act(acc), 0.0f);
            unsigned short hi = f2bf(h);
            unsigned short lo = f2bf(h - bf2f(hi));
            bufA[n*40 + (mb*4 + kg)]      = hi;
            bufA[n*40 + 16 + (mb*4 + kg)] = lo;
        }

        // prefetch next tile's x (covered by cells 2..4 latency)
        {
            int pt = tile + nw; if (pt > ntiles - 1) pt = ntiles - 1;
            const float* xp = x + (size_t)(pt*16 + n)*16 + (kg & 1)*8;
            xv0 = ((const float4*)xp)[0];
            xv1 = ((const float4*)xp)[1];
        }

        asm volatile("s_waitcnt lgkmcnt(0)" ::: "memory");
        FragCast f2c; f2c.u = *(const uint4*)&bufA[n*40 + kg*8];
        bf16x8 B2 = f2c.v;

        // ---- cell 2 (bias in K-slots) -> selu -> bufB ----
#pragma unroll
        for (int mb = 0; mb < 3; ++mb) {
            f32x4 acc = __builtin_amdgcn_mfma_f32_16x16x32_bf16(Afr[6 + mb*2+0], B2, z4, 0,0,0);
            acc       = __builtin_amdgcn_mfma_f32_16x16x32_bf16(Afr[6 + mb*2+1], B2, acc, 0,0,0);
            float v = cell_act(acc);
            float ev = ex2(v * L2E);                 // e^v, v in (-1,1)
            float s = (v > 0.0f) ? (1.0507009873554805f * v)
                                 : fmaf(ev, 1.7580993408473766f, -1.7580993408473766f);
            unsigned short hi = f2bf(s);
            unsigned short lo = f2bf(s - bf2f(hi));
            bufB[n*40 + (mb*4 + kg)]      = hi;
            bufB[n*40 + 16 + (mb*4 + kg)] = lo;
        }

        asm volatile("s_waitcnt lgkmcnt(0)" ::: "memory");
        FragCast f3c; f3c.u = *(const uint4*)&bufB[n*40 + kg*8];
        bf16x8 B3 = f3c.v;

        // ---- heads m, d (bias in K-slots) -> tanh -> store ----
        float* om = out + (size_t)row0 * 12;
        float* od = out + ((size_t)nrows + row0) * 12;
#pragma unroll
        for (int mb = 0; mb < 3; ++mb) {
            f32x4 am = __builtin_amdgcn_mfma_f32_16x16x32_bf16(Afr[12 + mb*2+0], B3, z4, 0,0,0);
            am       = __builtin_amdgcn_mfma_f32_16x16x32_bf16(Afr[12 + mb*2+1], B3, am, 0,0,0);
            f32x4 ad = __builtin_amdgcn_mfma_f32_16x16x32_bf16(Afr[18 + mb*2+0], B3, z4, 0,0,0);
            ad       = __builtin_amdgcn_mfma_f32_16x16x32_bf16(Afr[18 + mb*2+1], B3, ad, 0,0,0);
            om[mb*4 + kg] = tanh_pade(cell_act(am));
            od[mb*4 + kg] = tanh_pade(cell_act(ad));
        }
    }
}

extern "C" void kernel_launch(void* const* d_in, const int* in_sizes, int n_in,
                              void* d_out, int out_size, void* d_ws, size_t ws_size,
                              hipStream_t stream) {
    const float* x    = (const float*)d_in[0];
    const float* Wih1 = (const float*)d_in[1];
    const float* bih1 = (const float*)d_in[2];
    const float* bhh1 = (const float*)d_in[3];
    const float* Wih2 = (const float*)d_in[4];
    const float* bih2 = (const float*)d_in[5];
    const float* bhh2 = (const float*)d_in[6];
    const float* Wihm = (const float*)d_in[7];
    const float* bihm = (const float*)d_in[8];
    const float* bhhm = (const float*)d_in[9];
    const float* Wihd = (const float*)d_in[10];
    const float* bihd = (const float*)d_in[11];
    const float* bhhd = (const float*)d_in[12];
    float* out = (float*)d_out;

    unsigned short* wsA = (unsigned short*)d_ws;              // 24576 B
    float* wsB1 = (float*)((char*)d_ws + 24576);              // 3072 B

    prep_kernel<<<51, 256, 0, stream>>>(Wih1, bih1, bhh1, Wih2, bih2, bhh2,
                                        Wihm, bihm, bhhm, Wihd, bihd, bhhd,
                                        wsA, wsB1);

    int nrows = in_sizes[0] / 16;   // B = 1048576
    dynnet_kernel<<<2048, 256, 0, stream>>>(x, wsA, wsB1, out, nrows);
}

// Round 5
// 204.953 us; speedup vs baseline: 1.1276x; 1.0087x over previous
//
#include <hip/hip_runtime.h>
#include <hip/hip_bf16.h>

#define L2E 1.4426950408889634f

typedef float  f32x4  __attribute__((ext_vector_type(4)));
typedef short  bf16x8 __attribute__((ext_vector_type(8)));

__device__ __forceinline__ float ex2(float x){ return __builtin_amdgcn_exp2f(x); }
__device__ __forceinline__ float rcpf_(float x){ return __builtin_amdgcn_rcpf(x); }
__device__ __forceinline__ unsigned short f2bf(float f){          // RNE
    return __builtin_bit_cast(unsigned short, __float2bfloat16(f));
}
__device__ __forceinline__ float bf2f(unsigned short h){
    return __uint_as_float(((unsigned)h) << 16);
}
// pack value into one LDS word: low half = trunc-bf16(v) [k-slot 2j],
// high half = RNE-bf16(v - trunc(v)) [k-slot 2j+1]. hi+lo == v to ~2^-16 rel.
__device__ __forceinline__ unsigned pack_hl(float v){
    unsigned u   = __float_as_uint(v);
    float    rem = v - __uint_as_float(u & 0xFFFF0000u);
    unsigned lo  = f2bf(rem);
    return (u >> 16) | (lo << 16);
}

union FragCast { uint4 u; bf16x8 v; };
union BWords   { unsigned w[4]; bf16x8 v; };

// Gates arrive pre-scaled (i,o: -log2e ; g: -2log2e) so exp2 gives e^-i etc.
//   c = sig(i)*tanh(g) = (1-tg) * rcp((1+ei)(1+tg))
//   h = sig(o)*tanh(c) = c*P(c^2) * rcp((1+eo)*Q(c^2))   [Pade, |c|<1]
__device__ __forceinline__ float cell_act(f32x4 d){
    float ei = ex2(d.x), tg = ex2(d.y), eo = ex2(d.z);
    float rig = rcpf_((1.0f+ei)*(1.0f+tg));
    float c   = (1.0f-tg)*rig;
    float c2  = c*c;
    float num = c*(945.0f + c2*(105.0f + c2));
    float den = 945.0f + c2*(420.0f + 15.0f*c2);
    return num * rcpf_((1.0f+eo)*den);
}
__device__ __forceinline__ float tanh_pade(float x){
    float x2 = x*x;
    return x*(945.0f + x2*(105.0f + x2)) * rcpf_(945.0f + x2*(420.0f + 15.0f*x2));
}

// ---------------------------------------------------------------------------
// INTERLEAVED K layout: k-slot 2i = hi(src_i), 2i+1 = lo(src_i).
//   cell1 (K=16): i = x column 0..15, all 32 slots used, bias via C-init.
//   cells 2/m/d (K=12): i = h column 0..11 (slots 0..23); bias hi/lo at
//   k=24/25 against constant-1.0 B slots; 26..31 zero.
// Two A-frags per (cell,mb):
//   p=0: [2i]=Whi, [2i+1]=Whi  (+bias at 24/25)  -> Whi*(hi+lo) + bias
//   p=1: [2i]=Wlo, [2i+1]=0                      -> Wlo*hi
// ws layout: bytes [0,24576): 24 A-frags, fragid=((c*3+mb)*2+p), elem
//   (lane l, e): m=l&15, k=8*(l>>4)+e. Gate rows interleaved (i,g,o,pad)*12:
//   gr=mb*16+m, t3=gr&3, j=gr>>2.
// bytes [24576,27648): cell1 bias C-init f32x4 frags (i,g,o,0, prescaled).
// ---------------------------------------------------------------------------
__global__ void prep_kernel(
    const float* __restrict__ W1, const float* __restrict__ bi1, const float* __restrict__ bh1,
    const float* __restrict__ W2, const float* __restrict__ bi2, const float* __restrict__ bh2,
    const float* __restrict__ Wm, const float* __restrict__ bim, const float* __restrict__ bhm,
    const float* __restrict__ Wd, const float* __restrict__ bid, const float* __restrict__ bhd,
    unsigned short* __restrict__ wsA, float* __restrict__ wsB1)
{
    const float* Ws[4]  = {W1, W2, Wm, Wd};
    const float* bis[4] = {bi1, bi2, bim, bid};
    const float* bhs[4] = {bh1, bh2, bhm, bhd};
    const int goff[3] = {0, 24, 36};

    int t = blockIdx.x * blockDim.x + threadIdx.x;
    if (t < 12288) {
        int fragid = t >> 9;
        int le = t & 511;
        int l  = le >> 3, e = le & 7;
        int p  = fragid & 1;
        int cmb = fragid >> 1;
        int c  = cmb / 3, mb = cmb % 3;
        int m  = l & 15, kg = l >> 4;
        int k  = kg * 8 + e;
        int gr = mb * 16 + m;
        int t3 = gr & 3, j = gr >> 2;
        int K  = (c == 0) ? 16 : 12;
        int i  = k >> 1, odd = k & 1;
        unsigned short outv = 0;
        if (t3 < 3) {
            float gscv = (t3 == 1) ? (-2.0f * L2E) : (-L2E);
            if (i < K) {
                float full = gscv * Ws[c][(goff[t3] + j) * K + i];
                unsigned short hi = f2bf(full);
                if (p == 0) outv = hi;
                else        outv = odd ? 0 : f2bf(full - bf2f(hi));
            } else if (c > 0 && (k == 24 || k == 25) && p == 0) {
                float b = gscv * (bis[c][goff[t3] + j] + bhs[c][goff[t3] + j]);
                unsigned short hi = f2bf(b);
                outv = (k == 24) ? hi : f2bf(b - bf2f(hi));
            }
        }
        wsA[t] = outv;
    } else if (t < 13056) {
        int u = t - 12288;
        int r = u & 3, v = u >> 2;
        int l = v & 63, mb = v >> 6;
        float val = 0.0f;
        if (r < 3) {
            int gr = mb * 16 + ((l >> 4) * 4) + r;   // t3 == r
            int j  = gr >> 2;
            float gscv = (r == 1) ? (-2.0f * L2E) : (-L2E);
            val = gscv * (bis[0][goff[r] + j] + bhs[0][goff[r] + j]);
        }
        wsB1[u] = val;
    }
}

__global__ __launch_bounds__(256, 3) void dynnet_kernel(
    const float* __restrict__ x, const unsigned short* __restrict__ wsA,
    const float* __restrict__ wsB1, float* __restrict__ out, int nrows)
{
    // per-wave double buffer: 16 rows x 40 ushort (80B stride, 16B-aligned).
    // ushort slots 0..23: j-interleaved hi/lo (word j = hi_j|lo_j<<16),
    // slots 24,25 = 1.0 (bias lanes), 26..31 = 0.
    __shared__ __align__(16) unsigned short lds[4][2][640];
    const int lane = threadIdx.x & 63;
    const int wid  = threadIdx.x >> 6;
    const int n    = lane & 15;
    const int kg   = lane >> 4;
    unsigned short* bufA = &lds[wid][0][0];
    unsigned short* bufB = &lds[wid][1][0];

    if (lane < 16) {   // constant bias/pad slots, written once
        *(unsigned long long*)&bufA[lane*40 + 24] = 0x000000003F803F80ULL;
        *(unsigned long long*)&bufA[lane*40 + 28] = 0ULL;
        *(unsigned long long*)&bufB[lane*40 + 24] = 0x000000003F803F80ULL;
        *(unsigned long long*)&bufB[lane*40 + 28] = 0ULL;
    }

    // persistent weight fragments + cell1 bias C-init
    bf16x8 Afr[24];
    const uint4* wsA4 = (const uint4*)wsA;
#pragma unroll
    for (int f = 0; f < 24; ++f) {
        FragCast fc; fc.u = wsA4[f*64 + lane]; Afr[f] = fc.v;
    }
    f32x4 b1[3];
    const float4* wsB14 = (const float4*)wsB1;
#pragma unroll
    for (int mb = 0; mb < 3; ++mb) {
        float4 tb = wsB14[mb*64 + lane];
        b1[mb] = (f32x4){tb.x, tb.y, tb.z, tb.w};
    }

    const int ntiles = nrows >> 4;
    const int nw = gridDim.x * 4;
    int tile = blockIdx.x * 4 + wid;
    if (tile >= ntiles) return;

    // lane (n,kg) needs only x[row n][kg*4 .. kg*4+3]: one float4
    float4 xv = ((const float4*)(x + (size_t)(tile*16 + n)*16))[kg];

    const f32x4 z4 = {0.f, 0.f, 0.f, 0.f};

    for (; tile < ntiles; tile += nw) {
        // B-frag for cell1: word i = hi(x_i) | lo(x_i)<<16, i = kg*4..kg*4+3
        BWords xb;
        xb.w[0] = pack_hl(xv.x); xb.w[1] = pack_hl(xv.y);
        xb.w[2] = pack_hl(xv.z); xb.w[3] = pack_hl(xv.w);
        bf16x8 xB = xb.v;

        const int row0 = tile*16 + n;

        // ---- cell 1 (bias via C-init) -> relu -> bufA ----
#pragma unroll
        for (int mb = 0; mb < 3; ++mb) {
            f32x4 acc = __builtin_amdgcn_mfma_f32_16x16x32_bf16(Afr[mb*2+0], xB, b1[mb], 0,0,0);
            acc       = __builtin_amdgcn_mfma_f32_16x16x32_bf16(Afr[mb*2+1], xB, acc,    0,0,0);
            float h = fmaxf(cell_act(acc), 0.0f);
            *(unsigned*)&bufA[n*40 + (mb*4 + kg)*2] = pack_hl(h);
        }

        // prefetch next tile's x (covered by cells 2..4)
        {
            int pt = tile + nw; if (pt > ntiles - 1) pt = ntiles - 1;
            xv = ((const float4*)(x + (size_t)(pt*16 + n)*16))[kg];
        }

        asm volatile("s_waitcnt lgkmcnt(0)" ::: "memory");
        FragCast f2c; f2c.u = *(const uint4*)&bufA[n*40 + kg*8];
        bf16x8 B2 = f2c.v;

        // ---- cell 2 (bias in k=24/25) -> selu -> bufB ----
#pragma unroll
        for (int mb = 0; mb < 3; ++mb) {
            f32x4 acc = __builtin_amdgcn_mfma_f32_16x16x32_bf16(Afr[6 + mb*2+0], B2, z4, 0,0,0);
            acc       = __builtin_amdgcn_mfma_f32_16x16x32_bf16(Afr[6 + mb*2+1], B2, acc, 0,0,0);
            float v = cell_act(acc);
            float ev = ex2(v * L2E);                 // e^v, v in (-1,1)
            float s = (v > 0.0f) ? (1.0507009873554805f * v)
                                 : fmaf(ev, 1.7580993408473766f, -1.7580993408473766f);
            *(unsigned*)&bufB[n*40 + (mb*4 + kg)*2] = pack_hl(s);
        }

        asm volatile("s_waitcnt lgkmcnt(0)" ::: "memory");
        FragCast f3c; f3c.u = *(const uint4*)&bufB[n*40 + kg*8];
        bf16x8 B3 = f3c.v;

        // ---- heads m, d (bias in k=24/25) -> tanh -> store ----
        float* om = out + (size_t)row0 * 12;
        float* od = out + ((size_t)nrows + row0) * 12;
#pragma unroll
        for (int mb = 0; mb < 3; ++mb) {
            f32x4 am = __builtin_amdgcn_mfma_f32_16x16x32_bf16(Afr[12 + mb*2+0], B3, z4, 0,0,0);
            am       = __builtin_amdgcn_mfma_f32_16x16x32_bf16(Afr[12 + mb*2+1], B3, am, 0,0,0);
            f32x4 ad = __builtin_amdgcn_mfma_f32_16x16x32_bf16(Afr[18 + mb*2+0], B3, z4, 0,0,0);
            ad       = __builtin_amdgcn_mfma_f32_16x16x32_bf16(Afr[18 + mb*2+1], B3, ad, 0,0,0);
            om[mb*4 + kg] = tanh_pade(cell_act(am));
            od[mb*4 + kg] = tanh_pade(cell_act(ad));
        }
    }
}

extern "C" void kernel_launch(void* const* d_in, const int* in_sizes, int n_in,
                              void* d_out, int out_size, void* d_ws, size_t ws_size,
                              hipStream_t stream) {
    const float* x    = (const float*)d_in[0];
    const float* Wih1 = (const float*)d_in[1];
    const float* bih1 = (const float*)d_in[2];
    const float* bhh1 = (const float*)d_in[3];
    const float* Wih2 = (const float*)d_in[4];
    const float* bih2 = (const float*)d_in[5];
    const float* bhh2 = (const float*)d_in[6];
    const float* Wihm = (const float*)d_in[7];
    const float* bihm = (const float*)d_in[8];
    const float* bhhm = (const float*)d_in[9];
    const float* Wihd = (const float*)d_in[10];
    const float* bihd = (const float*)d_in[11];
    const float* bhhd = (const float*)d_in[12];
    float* out = (float*)d_out;

    unsigned short* wsA = (unsigned short*)d_ws;              // 24576 B
    float* wsB1 = (float*)((char*)d_ws + 24576);              // 3072 B

    prep_kernel<<<51, 256, 0, stream>>>(Wih1, bih1, bhh1, Wih2, bih2, bhh2,
                                        Wihm, bihm, bhhm, Wihd, bihd, bhhd,
                                        wsA, wsB1);

    int nrows = in_sizes[0] / 16;   // B = 1048576
    dynnet_kernel<<<2048, 256, 0, stream>>>(x, wsA, wsB1, out, nrows);
}